// Round 7
// baseline (41.042 us; speedup 1.0000x reference)
//
#include <hip/hip_runtime.h>
#include <hip/hip_bf16.h>

// RotT: M = expm(-0.5i*angle*S), S = |0><1|+|1><0| on qudit 7 of 15 qutrits.
// For planes j=0,1:  yr = c*xr[e] + s*xi[partner],  yi = c*xi[e] - s*xr[partner]
// partner = e+2187 (j=0) or e-2187 (j=1). Plane j=2 is passthrough.
// c=cos(angle/2), s=sin(angle/2).
//
// Output (verified round 4): 2*D bf16 interleaved IMAG-FIRST:
//   u32 per amplitude = (bf16(re)<<16) | bf16(im).
//
// Rounds 5-6 post-mortem: LDS staging lost twice (occupancy collapse, then
// 3.57M bank conflicts from 16B-lane-stride scalar LDS reads). This round:
// NO LDS. Process aligned quads of 4 consecutive global elements e (e%4==0):
// self loads float4-aligned, stores uint4-aligned. Since 2187 % 4 == 3, the
// partner quad lives at a COMPILE-TIME offset inside two aligned float4s:
//   j=0: {a.w,b.x,b.y,b.z} of loads at e+2184, e+2188
//   j=1: {a.y,a.z,a.w,b.x} of loads at e-2188, e-2184
// Overlapping partner lines are L1/L2 hits. ~4400 plane-boundary quads take
// a scalar fallback.

constexpr int PLANE = 2187;        // 3^7
constexpr int D     = 14348907;    // 3^15
constexpr int NQUAD = (D + 3) >> 2;

__device__ __forceinline__ uint32_t pack_bf2(float re, float im) {
    __hip_bfloat162 h;
    h.x = __float2bfloat16(im);    // low half  = imag (verified layout)
    h.y = __float2bfloat16(re);    // high half = real
    return *reinterpret_cast<uint32_t*>(&h);
}

__device__ __forceinline__ float4 ld4(const float* p) {
    return *reinterpret_cast<const float4*>(p);
}

__global__ __launch_bounds__(256) void rot_kernel(
    const float* __restrict__ xr,
    const float* __restrict__ xi,
    const float* __restrict__ angle,
    uint32_t* __restrict__ out)
{
    const int q = blockIdx.x * blockDim.x + threadIdx.x;
    if (q >= NQUAD) return;
    const int e = q << 2;

    const float half = 0.5f * angle[0];
    const float s = sinf(half);
    const float c = cosf(half);

    const int t = e / PLANE;       // global plane index (magic-mul)
    const int j = t % 3;
    const int b = e - t * PLANE;

    if (b + 3 < PLANE && e + 3 < D) {
        // ---- fast path: whole quad in one plane; everything 16B-aligned ----
        const float4 sr = ld4(xr + e);
        const float4 si = ld4(xi + e);
        uint4 o;
        if (j == 2) {
            o.x = pack_bf2(sr.x, si.x); o.y = pack_bf2(sr.y, si.y);
            o.z = pack_bf2(sr.z, si.z); o.w = pack_bf2(sr.w, si.w);
        } else {
            float pr0, pr1, pr2, pr3, pi0, pi1, pi2, pi3;
            if (j == 0) {
                const int pb = e + 2184;           // partner = e+2187 = pb+3
                float4 ar = ld4(xr + pb), br = ld4(xr + pb + 4);
                float4 ai = ld4(xi + pb), bi = ld4(xi + pb + 4);
                pr0 = ar.w; pr1 = br.x; pr2 = br.y; pr3 = br.z;
                pi0 = ai.w; pi1 = bi.x; pi2 = bi.y; pi3 = bi.z;
            } else {
                const int pb = e - 2188;           // partner = e-2187 = pb+1
                float4 ar = ld4(xr + pb), br = ld4(xr + pb + 4);
                float4 ai = ld4(xi + pb), bi = ld4(xi + pb + 4);
                pr0 = ar.y; pr1 = ar.z; pr2 = ar.w; pr3 = br.x;
                pi0 = ai.y; pi1 = ai.z; pi2 = ai.w; pi3 = bi.x;
            }
            o.x = pack_bf2(c * sr.x + s * pi0, c * si.x - s * pr0);
            o.y = pack_bf2(c * sr.y + s * pi1, c * si.y - s * pr1);
            o.z = pack_bf2(c * sr.z + s * pi2, c * si.z - s * pr2);
            o.w = pack_bf2(c * sr.w + s * pi3, c * si.w - s * pr3);
        }
        *reinterpret_cast<uint4*>(out + e) = o;
    } else {
        // ---- slow path: quad straddles a plane boundary (or array end) ----
        #pragma unroll
        for (int k = 0; k < 4; ++k) {
            int e2 = e + k;
            if (e2 >= D) break;
            int t2 = e2 / PLANE;
            int j2 = t2 % 3;
            float r = xr[e2], i = xi[e2];
            if (j2 == 2) {
                out[e2] = pack_bf2(r, i);
            } else {
                int p = e2 + ((j2 == 0) ? PLANE : -PLANE);
                out[e2] = pack_bf2(c * r + s * xi[p], c * i - s * xr[p]);
            }
        }
    }
}

extern "C" void kernel_launch(void* const* d_in, const int* in_sizes, int n_in,
                              void* d_out, int out_size, void* d_ws, size_t ws_size,
                              hipStream_t stream) {
    // Inputs in setup_inputs() dict order: x_real (D), x_imag (D), angle (1).
    const float* big[2] = {nullptr, nullptr};
    const float* angle = nullptr;
    int nbig = 0;
    for (int i = 0; i < n_in; ++i) {
        if (in_sizes[i] == 1) angle = (const float*)d_in[i];
        else if (nbig < 2)    big[nbig++] = (const float*)d_in[i];
    }
    const float* xr = big[0];
    const float* xi = big[1];
    uint32_t* out = (uint32_t*)d_out;

    const int block = 256;
    const int grid = (NQUAD + block - 1) / block;
    rot_kernel<<<grid, block, 0, stream>>>(xr, xi, angle, out);
}

// Round 8
// 34.276 us; speedup vs baseline: 1.1974x; 1.1974x over previous
//
#include <hip/hip_runtime.h>
#include <hip/hip_bf16.h>

// RotT: apply M = expm(-0.5i*angle*S), S = |0><1|+|1><0| (qutrit, levels 0,1),
// on qudit INDEX=7 of NQ=15 qutrits. d_left = d_right = 3^7 = 2187.
// M = [[c, -i s, 0], [-i s, c, 0], [0, 0, 1]], c=cos(angle/2), s=sin(angle/2).
//
// Output (verified round 4): 2*D bf16, interleaved IMAG-FIRST:
//   u32 per amplitude = (bf16(re) << 16) | bf16(im).
//
// Structure = round-4 champion (32.7 us, exactly HBM-traffic-bound:
// (63+57.6) MB / 32.7 us = 3.69 TB/s). Rounds 5-7 showed vectorization adds
// traffic or LDS costs. This round's single change: NONTEMPORAL stores (the
// output is never re-read; no-allocate keeps the 256 MB L3 filled with input
// lines across graph replays -> FETCH_SIZE should drop below 63 MB).

constexpr int DR = 2187;            // 3^7  (d_right)
constexpr int ROWSTRIDE = 3 * DR;   // 6561
constexpr int NPAIRS = 4782969;     // 3^14 = d_left * d_right

__device__ __forceinline__ uint32_t pack_bf2(float re, float im) {
    __hip_bfloat162 h;
    h.x = __float2bfloat16(im);      // low half  = imag (verified layout)
    h.y = __float2bfloat16(re);      // high half = real
    return *reinterpret_cast<uint32_t*>(&h);
}

__global__ __launch_bounds__(256) void rot_kernel(
    const float* __restrict__ xr,
    const float* __restrict__ xi,
    const float* __restrict__ angle,
    uint32_t* __restrict__ out)
{
    int p = blockIdx.x * blockDim.x + threadIdx.x;
    if (p >= NPAIRS) return;

    float half = 0.5f * angle[0];
    float s = sinf(half);
    float c = cosf(half);

    int a = p / DR;                 // compiler magic-mul
    int b = p - a * DR;
    int base = a * ROWSTRIDE + b;   // amplitude index of (a, j=0, b)

    float x0r = xr[base],          x0i = xi[base];
    float x1r = xr[base + DR],     x1i = xi[base + DR];
    float x2r = xr[base + 2 * DR], x2i = xi[base + 2 * DR];

    // y0 = c*x0 - i*s*x1 ; y1 = -i*s*x0 + c*x1 ; y2 = x2
    float y0r = c * x0r + s * x1i;
    float y0i = c * x0i - s * x1r;
    float y1r = s * x0i + c * x1r;
    float y1i = c * x1i - s * x0r;

    __builtin_nontemporal_store(pack_bf2(y0r, y0i), out + base);
    __builtin_nontemporal_store(pack_bf2(y1r, y1i), out + base + DR);
    __builtin_nontemporal_store(pack_bf2(x2r, x2i), out + base + 2 * DR);
}

extern "C" void kernel_launch(void* const* d_in, const int* in_sizes, int n_in,
                              void* d_out, int out_size, void* d_ws, size_t ws_size,
                              hipStream_t stream) {
    // Inputs in setup_inputs() dict order: x_real (D), x_imag (D), angle (1).
    const float* big[2] = {nullptr, nullptr};
    const float* angle = nullptr;
    int nbig = 0;
    for (int i = 0; i < n_in; ++i) {
        if (in_sizes[i] == 1) angle = (const float*)d_in[i];
        else if (nbig < 2)    big[nbig++] = (const float*)d_in[i];
    }
    const float* xr = big[0];
    const float* xi = big[1];
    uint32_t* out = (uint32_t*)d_out;

    const int block = 256;
    const int grid = (NPAIRS + block - 1) / block;
    rot_kernel<<<grid, block, 0, stream>>>(xr, xi, angle, out);
}

// Round 9
// 33.845 us; speedup vs baseline: 1.2127x; 1.0127x over previous
//
#include <hip/hip_runtime.h>
#include <hip/hip_bf16.h>

// RotT: apply M = expm(-0.5i*angle*S), S = |0><1|+|1><0| (qutrit, levels 0,1),
// on qudit INDEX=7 of NQ=15 qutrits. d_left = d_right = 3^7 = 2187.
// y0 = c*x0 - i*s*x1 ; y1 = -i*s*x0 + c*x1 ; y2 = x2; c=cos(angle/2), s=sin(angle/2).
//
// Output (verified round 4): 2*D bf16, interleaved IMAG-FIRST:
//   u32 per amplitude = (bf16(re) << 16) | bf16(im).
//
// History: r4 scalar champion 32.7us (120.6MB HBM = 3.69TB/s, VALUBusy 21%,
// occ 70% -> latency-bound, not BW-bound). r5/r6 LDS staging lost (occupancy,
// then 3.57M bank conflicts). r7 partner-quad reload lost (FETCH +52%).
// r8 NT stores neutral (FETCH unchanged 63.0MB).
// This round: MLP x4 — each thread handles 4 pairs at grid-span stride S,
// preserving r4's exact per-wave coalescing and single-touch traffic, with
// ~24 independent loads in flight per thread.

constexpr int DR = 2187;            // 3^7  (d_right)
constexpr int ROWSTRIDE = 3 * DR;   // 6561
constexpr int NPAIRS = 4782969;     // 3^14 = d_left * d_right
constexpr int BLOCK = 256;
constexpr int GRID  = 4671;         // ceil(NPAIRS/4/256)
constexpr int SPAN  = GRID * BLOCK; // 1195776; 4*SPAN - NPAIRS = 135 tail slots

__device__ __forceinline__ uint32_t pack_bf2(float re, float im) {
    __hip_bfloat162 h;
    h.x = __float2bfloat16(im);      // low half  = imag (verified layout)
    h.y = __float2bfloat16(re);      // high half = real
    return *reinterpret_cast<uint32_t*>(&h);
}

__global__ __launch_bounds__(256) void rot_kernel(
    const float* __restrict__ xr,
    const float* __restrict__ xi,
    const float* __restrict__ angle,
    uint32_t* __restrict__ out)
{
    const int p0 = blockIdx.x * BLOCK + threadIdx.x;

    const float half = 0.5f * angle[0];
    const float s = sinf(half);
    const float c = cosf(half);

    int  base[4];
    bool act[4];
    #pragma unroll
    for (int k = 0; k < 4; ++k) {
        int p = p0 + k * SPAN;
        act[k] = (p < NPAIRS);
        int pp = act[k] ? p : 0;
        int a = pp / DR;             // compiler magic-mul
        int b = pp - a * DR;
        base[k] = a * ROWSTRIDE + b;
    }

    // issue all loads (independent -> deep MLP); static indices only
    float x0r[4], x0i[4], x1r[4], x1i[4], x2r[4], x2i[4];
    #pragma unroll
    for (int k = 0; k < 4; ++k) {
        if (act[k]) {
            x0r[k] = xr[base[k]];
            x1r[k] = xr[base[k] + DR];
            x2r[k] = xr[base[k] + 2 * DR];
            x0i[k] = xi[base[k]];
            x1i[k] = xi[base[k] + DR];
            x2i[k] = xi[base[k] + 2 * DR];
        }
    }

    #pragma unroll
    for (int k = 0; k < 4; ++k) {
        if (act[k]) {
            float y0r = c * x0r[k] + s * x1i[k];
            float y0i = c * x0i[k] - s * x1r[k];
            float y1r = s * x0i[k] + c * x1r[k];
            float y1i = c * x1i[k] - s * x0r[k];
            out[base[k]]          = pack_bf2(y0r, y0i);
            out[base[k] + DR]     = pack_bf2(y1r, y1i);
            out[base[k] + 2 * DR] = pack_bf2(x2r[k], x2i[k]);
        }
    }
}

extern "C" void kernel_launch(void* const* d_in, const int* in_sizes, int n_in,
                              void* d_out, int out_size, void* d_ws, size_t ws_size,
                              hipStream_t stream) {
    // Inputs in setup_inputs() dict order: x_real (D), x_imag (D), angle (1).
    const float* big[2] = {nullptr, nullptr};
    const float* angle = nullptr;
    int nbig = 0;
    for (int i = 0; i < n_in; ++i) {
        if (in_sizes[i] == 1) angle = (const float*)d_in[i];
        else if (nbig < 2)    big[nbig++] = (const float*)d_in[i];
    }
    const float* xr = big[0];
    const float* xi = big[1];
    uint32_t* out = (uint32_t*)d_out;

    rot_kernel<<<GRID, BLOCK, 0, stream>>>(xr, xi, angle, out);
}

// Round 10
// 32.826 us; speedup vs baseline: 1.2503x; 1.0310x over previous
//
#include <hip/hip_runtime.h>
#include <hip/hip_bf16.h>

// RotT: apply M = expm(-0.5i*angle*S), S = |0><1|+|1><0| (qutrit, levels 0,1),
// on qudit INDEX=7 of NQ=15 qutrits. d_left = d_right = 3^7 = 2187.
// M = [[c, -i s, 0], [-i s, c, 0], [0, 0, 1]], c=cos(angle/2), s=sin(angle/2).
// y0 = c*x0 - i*s*x1 ; y1 = -i*s*x0 + c*x1 ; y2 = x2.
//
// Output (verified): 2*D bf16, interleaved IMAG-FIRST:
//   u32 per amplitude = (bf16(re) << 16) | bf16(im).
//
// FINAL = round-4 champion (32.7 us). Optimization ledger (all measured):
//  r5 LDS staging @256thr: occupancy 70->33%, 35.5us — LOST
//  r6 LDS staging @512thr: 3.57M bank conflicts (16B-lane-stride reads), 37.8us — LOST
//  r7 no-LDS partner-quad reload: FETCH 63->95.6MB (+52%), 41.0us — LOST
//  r8 nontemporal stores: FETCH unchanged 63.0MB, 34.3us — NEUTRAL
//  r9 MLP x4 grid-span: counters identical, VALUBusy 21->13%, 33.8us — NEUTRAL
// Roofline argument: traffic is single-touch minimal (FETCH 63MB < 114.8MB
// logical thanks to L3; WRITE 57.6MB = output size; 0 conflicts). 120.6MB at
// 32.7us = 3.69TB/s effective service rate for this r/w mix; issue-side
// latency and traffic levers exhausted above. This is the practical floor.

constexpr int DR = 2187;            // 3^7  (d_right)
constexpr int ROWSTRIDE = 3 * DR;   // 6561
constexpr int NPAIRS = 4782969;     // 3^14 = d_left * d_right

__device__ __forceinline__ uint32_t pack_bf2(float re, float im) {
    __hip_bfloat162 h;
    h.x = __float2bfloat16(im);      // low half  = imag (verified layout)
    h.y = __float2bfloat16(re);      // high half = real
    return *reinterpret_cast<uint32_t*>(&h);
}

__global__ __launch_bounds__(256) void rot_kernel(
    const float* __restrict__ xr,
    const float* __restrict__ xi,
    const float* __restrict__ angle,
    uint32_t* __restrict__ out)
{
    int p = blockIdx.x * blockDim.x + threadIdx.x;
    if (p >= NPAIRS) return;

    float half = 0.5f * angle[0];
    float s = sinf(half);
    float c = cosf(half);

    int a = p / DR;                 // compiler magic-mul
    int b = p - a * DR;
    int base = a * ROWSTRIDE + b;   // amplitude index of (a, j=0, b)

    float x0r = xr[base],          x0i = xi[base];
    float x1r = xr[base + DR],     x1i = xi[base + DR];
    float x2r = xr[base + 2 * DR], x2i = xi[base + 2 * DR];

    float y0r = c * x0r + s * x1i;
    float y0i = c * x0i - s * x1r;
    float y1r = s * x0i + c * x1r;
    float y1i = c * x1i - s * x0r;

    out[base]          = pack_bf2(y0r, y0i);
    out[base + DR]     = pack_bf2(y1r, y1i);
    out[base + 2 * DR] = pack_bf2(x2r, x2i);
}

extern "C" void kernel_launch(void* const* d_in, const int* in_sizes, int n_in,
                              void* d_out, int out_size, void* d_ws, size_t ws_size,
                              hipStream_t stream) {
    // Inputs in setup_inputs() dict order: x_real (D), x_imag (D), angle (1).
    const float* big[2] = {nullptr, nullptr};
    const float* angle = nullptr;
    int nbig = 0;
    for (int i = 0; i < n_in; ++i) {
        if (in_sizes[i] == 1) angle = (const float*)d_in[i];
        else if (nbig < 2)    big[nbig++] = (const float*)d_in[i];
    }
    const float* xr = big[0];
    const float* xi = big[1];
    uint32_t* out = (uint32_t*)d_out;

    const int block = 256;
    const int grid = (NPAIRS + block - 1) / block;
    rot_kernel<<<grid, block, 0, stream>>>(xr, xi, angle, out);
}